// Round 22
// baseline (116.421 us; speedup 1.0000x reference)
//
#include <hip/hip_runtime.h>
#include <math.h>

// Problem constants: B=16, C=256, H=W=64, N=4096, GROUPS=16 (cg=16), HEADS=8 (ch=32)

__device__ __forceinline__ float sigmoidf_(float v) { return 1.0f / (1.0f + __expf(-v)); }

typedef _Float16 half8 __attribute__((ext_vector_type(8)));
typedef _Float16 half4 __attribute__((ext_vector_type(4)));
typedef float f32x4 __attribute__((ext_vector_type(4)));

#define GLOAD_LDS16(gp, lp)                                                     \
    __builtin_amdgcn_global_load_lds(                                           \
        (const __attribute__((address_space(1))) void*)(gp),                    \
        (__attribute__((address_space(3))) void*)(lp), 16, 0, 0)

// ---------------------------------------------------------------------------
// prep_fused: X (fp32) -> Xh + Xt; blocks with blockIdx.x>=64 convert weights.
// ---------------------------------------------------------------------------
__global__ __launch_bounds__(256) void prep_fused(
    const float* __restrict__ X, _Float16* __restrict__ Xh, _Float16* __restrict__ Xt,
    const float* __restrict__ wqkv, const float* __restrict__ wproj,
    _Float16* __restrict__ wqkvh, _Float16* __restrict__ wprojh)
{
    __shared__ float tl[64][68];
    if (blockIdx.x >= 64) {
        const int blk = (blockIdx.x - 64) * 64 + blockIdx.y * 16 + blockIdx.z;
        if (blk < 192) {
            const long i = ((long)blk * 256 + threadIdx.x) * 4;
            const float4 v = *(const float4*)(wqkv + i);
            half4 h = { (_Float16)v.x, (_Float16)v.y, (_Float16)v.z, (_Float16)v.w };
            *(half4*)(wqkvh + i) = h;
        } else {
            const long i = ((long)(blk - 192) * 256 + threadIdx.x) * 4;
            const float4 v = *(const float4*)(wproj + i);
            half4 h = { (_Float16)v.x, (_Float16)v.y, (_Float16)v.z, (_Float16)v.w };
            *(half4*)(wprojh + i) = h;
        }
        return;
    }
    const int b = blockIdx.z, c0 = blockIdx.y * 64, n0 = blockIdx.x * 64;
    const int t = threadIdx.x;
    const int r0 = t >> 4;
    const int q = (t & 15) * 4;
    const float* Xb = X + ((long)b * 256 + c0) * 4096 + n0;
    _Float16* Xhb = Xh + ((long)b * 256 + c0) * 4096 + n0;
    #pragma unroll
    for (int i = 0; i < 4; ++i) {
        const int r = r0 + i * 16;
        const float4 v = *(const float4*)(Xb + (long)r * 4096 + q);
        tl[r][q + 0] = v.x; tl[r][q + 1] = v.y;
        tl[r][q + 2] = v.z; tl[r][q + 3] = v.w;
        half4 h = { (_Float16)v.x, (_Float16)v.y, (_Float16)v.z, (_Float16)v.w };
        *(half4*)(Xhb + (long)r * 4096 + q) = h;
    }
    __syncthreads();
    const int nn = t >> 2, cc = (t & 3) * 16;
    _Float16* Xtb = Xt + ((long)b * 4096 + n0 + nn) * 256 + c0 + cc;
    half8 o0, o1;
    #pragma unroll
    for (int k = 0; k < 8; ++k) o0[k] = (_Float16)tl[cc + k][nn];
    #pragma unroll
    for (int k = 0; k < 8; ++k) o1[k] = (_Float16)tl[cc + 8 + k][nn];
    *(half8*)(Xtb) = o0;
    *(half8*)(Xtb + 8) = o1;
}

// ---------------------------------------------------------------------------
// Gram split-K, SYMMETRIC, f16 partials (R19-validated).
// ---------------------------------------------------------------------------
__global__ __launch_bounds__(256) void gram_split(const _Float16* __restrict__ Xh,
                                                  _Float16* __restrict__ pGh)
{
    __shared__ _Float16 Al[128 * 32];
    __shared__ _Float16 Bl[128 * 32];
    const int hw = blockIdx.x + 3 * blockIdx.y;
    const int f  = (hw & 7) * 48 + (hw >> 3);
    const int tile = f % 3;
    const int bz = f / 3;
    const int b = bz >> 3, s = bz & 7;
    const int m0 = (tile == 1) ? 128 : 0;
    const int n0 = (tile == 0) ? 0 : 128;
    const _Float16* Xb = Xh + (long)b * 256 * 4096;
    const int t = threadIdx.x, lane = t & 63, wv = t >> 6;
    const int wm = (wv >> 1) * 64, wn = (wv & 1) * 64;
    f32x4 acc[4][4] = {};

    const int kbeg = s * 512, kend = kbeg + 512;
    for (int k0 = kbeg; k0 < kend; k0 += 32) {
        __syncthreads();
        #pragma unroll
        for (int r = 0; r < 2; ++r) {
            const int e = (r * 256 + t) * 8;
            const int row = e >> 5, col = e & 31;
            GLOAD_LDS16(Xb + (long)(m0 + row) * 4096 + k0 + col, &Al[e]);
            GLOAD_LDS16(Xb + (long)(n0 + row) * 4096 + k0 + col, &Bl[e]);
        }
        __syncthreads();
        half8 af[4], bf[4];
        #pragma unroll
        for (int ff = 0; ff < 4; ++ff) {
            af[ff] = *(const half8*)&Al[(wm + ff * 16 + (lane & 15)) * 32 + (lane >> 4) * 8];
            bf[ff] = *(const half8*)&Bl[(wn + ff * 16 + (lane & 15)) * 32 + (lane >> 4) * 8];
        }
        #pragma unroll
        for (int i = 0; i < 4; ++i)
            #pragma unroll
            for (int j = 0; j < 4; ++j)
                acc[i][j] = __builtin_amdgcn_mfma_f32_16x16x32_f16(af[i], bf[j], acc[i][j], 0, 0, 0);
    }
    _Float16* pGb = pGh + (long)s * 1048576 + (long)b * 65536;
    #pragma unroll
    for (int i = 0; i < 4; ++i)
        #pragma unroll
        for (int j = 0; j < 4; ++j) {
            const int row = m0 + wm + i * 16 + (lane >> 4) * 4;
            const int col = n0 + wn + j * 16 + (lane & 15);
            _Float16* gp = pGb + (long)row * 256 + col;
            #pragma unroll
            for (int r = 0; r < 4; ++r) gp[(long)r * 256] = (_Float16)acc[i][j][r];
        }
}

// ---------------------------------------------------------------------------
// reduce_mirror (R19-validated).
// ---------------------------------------------------------------------------
__global__ __launch_bounds__(256) void reduce_mirror(const _Float16* __restrict__ pGh,
                                                     _Float16* __restrict__ Gh)
{
    __shared__ _Float16 tl[64][72];
    const int idx = blockIdx.x, b = blockIdx.y;
    int ty, tx;
    bool mirror = false;
    if (idx < 4)       { ty = idx >> 1;        tx = idx & 1; }
    else if (idx < 8)  { ty = 2 + ((idx - 4) >> 1); tx = 2 + ((idx - 4) & 1); }
    else               { ty = (idx - 8) >> 1;  tx = 2 + ((idx - 8) & 1); mirror = true; }
    const int r0 = ty * 64, c0 = tx * 64;
    const int t = threadIdx.x;
    const int ii = t >> 2, jj = (t & 3) * 16;

    const _Float16* pGb = pGh + (long)b * 65536 + (long)(r0 + ii) * 256 + c0 + jj;
    _Float16* Gb = Gh + (long)b * 65536;
    _Float16 hv[16];
    #pragma unroll
    for (int q = 0; q < 4; ++q) {
        f32x4 s = {};
        #pragma unroll
        for (int k = 0; k < 8; ++k) {
            const half4 v = *(const half4*)(pGb + (long)k * 1048576 + q * 4);
            s[0] += (float)v[0]; s[1] += (float)v[1];
            s[2] += (float)v[2]; s[3] += (float)v[3];
        }
        hv[q * 4 + 0] = (_Float16)s[0]; hv[q * 4 + 1] = (_Float16)s[1];
        hv[q * 4 + 2] = (_Float16)s[2]; hv[q * 4 + 3] = (_Float16)s[3];
    }
    *(half8*)(Gb + (long)(r0 + ii) * 256 + c0 + jj)     = *(half8*)&hv[0];
    *(half8*)(Gb + (long)(r0 + ii) * 256 + c0 + jj + 8) = *(half8*)&hv[8];

    if (mirror) {
        #pragma unroll
        for (int k = 0; k < 16; ++k) tl[ii][jj + k] = hv[k];
        __syncthreads();
        half8 o0, o1;
        #pragma unroll
        for (int k = 0; k < 8; ++k) o0[k] = tl[jj + k][ii];
        #pragma unroll
        for (int k = 0; k < 8; ++k) o1[k] = tl[jj + 8 + k][ii];
        *(half8*)(Gb + (long)(c0 + ii) * 256 + r0 + jj)     = o0;
        *(half8*)(Gb + (long)(c0 + ii) * 256 + r0 + jj + 8) = o1;
    }
}

// ---------------------------------------------------------------------------
// mfma_bt (R19-validated).
// ---------------------------------------------------------------------------
template <bool DIAG, bool F16OUT>
__global__ __launch_bounds__(256) void mfma_bt(
    const _Float16* __restrict__ A, const _Float16* __restrict__ B,
    float* __restrict__ Cf, _Float16* __restrict__ Ch,
    long sA, long sB, long sC)
{
    __shared__ _Float16 Al[128 * 32];
    __shared__ _Float16 Bl[128 * 32];
    const int b = blockIdx.z;
    const int m0 = blockIdx.y * 128;
    const int n0 = DIAG ? m0 : blockIdx.x * 128;
    const _Float16* Ab = A + (long)b * sA;
    const _Float16* Bb = B + (long)b * sB;
    const int t = threadIdx.x, lane = t & 63, wv = t >> 6;
    const int wm = (wv >> 1) * 64, wn = (wv & 1) * 64;
    f32x4 acc[4][4] = {};

    for (int k0 = 0; k0 < 256; k0 += 32) {
        __syncthreads();
        #pragma unroll
        for (int r = 0; r < 2; ++r) {
            const int e = (r * 256 + t) * 8;
            const int row = e >> 5, col = e & 31;
            GLOAD_LDS16(Ab + (long)(m0 + row) * 256 + k0 + col, &Al[e]);
            GLOAD_LDS16(Bb + (long)(n0 + row) * 256 + k0 + col, &Bl[e]);
        }
        __syncthreads();
        half8 af[4], bf[4];
        #pragma unroll
        for (int ff = 0; ff < 4; ++ff) {
            af[ff] = *(const half8*)&Al[(wm + ff * 16 + (lane & 15)) * 32 + (lane >> 4) * 8];
            bf[ff] = *(const half8*)&Bl[(wn + ff * 16 + (lane & 15)) * 32 + (lane >> 4) * 8];
        }
        #pragma unroll
        for (int i = 0; i < 4; ++i)
            #pragma unroll
            for (int j = 0; j < 4; ++j)
                acc[i][j] = __builtin_amdgcn_mfma_f32_16x16x32_f16(af[i], bf[j], acc[i][j], 0, 0, 0);
    }
    #pragma unroll
    for (int i = 0; i < 4; ++i)
        #pragma unroll
        for (int j = 0; j < 4; ++j) {
            const int row = m0 + wm + i * 16 + (lane >> 4) * 4;
            const int col = n0 + wn + j * 16 + (lane & 15);
            #pragma unroll
            for (int r = 0; r < 4; ++r) {
                if (F16OUT)
                    Ch[(long)b * sC + (long)(row + r) * 256 + col] = (_Float16)acc[i][j][r];
                else
                    Cf[(long)b * sC + (long)(row + r) * 256 + col] = acc[i][j][r];
            }
        }
}

// ---------------------------------------------------------------------------
// mfma_pw (R17/R19-validated).
// ---------------------------------------------------------------------------
__global__ __launch_bounds__(256) void mfma_pw(
    const _Float16* __restrict__ A, const _Float16* __restrict__ B,
    _Float16* __restrict__ Ch, const float* __restrict__ gnb,
    _Float16* __restrict__ W2h)
{
    __shared__ _Float16 Al[128 * 32];
    __shared__ _Float16 Bl[128 * 32];
    const int b = blockIdx.z;
    const int m0 = blockIdx.y * 128;
    const int n0 = blockIdx.x * 128;
    const _Float16* Ab = A;
    const _Float16* Bb = B + (long)b * 65536;
    const int t = threadIdx.x, lane = t & 63, wv = t >> 6;
    const int wm = (wv >> 1) * 64, wn = (wv & 1) * 64;
    f32x4 acc[4][4] = {};

    for (int k0 = 0; k0 < 256; k0 += 32) {
        __syncthreads();
        #pragma unroll
        for (int r = 0; r < 2; ++r) {
            const int e = (r * 256 + t) * 8;
            const int row = e >> 5, col = e & 31;
            GLOAD_LDS16(Ab + (long)(m0 + row) * 256 + k0 + col, &Al[e]);
            GLOAD_LDS16(Bb + (long)(n0 + row) * 256 + k0 + col, &Bl[e]);
        }
        __syncthreads();
        half8 af[4], bf[4];
        #pragma unroll
        for (int ff = 0; ff < 4; ++ff) {
            af[ff] = *(const half8*)&Al[(wm + ff * 16 + (lane & 15)) * 32 + (lane >> 4) * 8];
            bf[ff] = *(const half8*)&Bl[(wn + ff * 16 + (lane & 15)) * 32 + (lane >> 4) * 8];
        }
        #pragma unroll
        for (int i = 0; i < 4; ++i)
            #pragma unroll
            for (int j = 0; j < 4; ++j)
                acc[i][j] = __builtin_amdgcn_mfma_f32_16x16x32_f16(af[i], bf[j], acc[i][j], 0, 0, 0);
    }
    #pragma unroll
    for (int i = 0; i < 4; ++i)
        #pragma unroll
        for (int j = 0; j < 4; ++j) {
            const int row = m0 + wm + i * 16 + (lane >> 4) * 4;
            const int col = n0 + wn + j * 16 + (lane & 15);
            #pragma unroll
            for (int r = 0; r < 4; ++r)
                Ch[(long)b * 65536 + (long)(row + r) * 256 + col] = (_Float16)acc[i][j][r];
        }
    float e[16];
    {
        float mx = -1e30f;
        #pragma unroll
        for (int c = 0; c < 16; ++c) mx = fmaxf(mx, gnb[c]);
        float s = 0.f;
        #pragma unroll
        for (int c = 0; c < 16; ++c) { e[c] = __expf(gnb[c] - mx); s += e[c]; }
        const float inv = 1.0f / s;
        #pragma unroll
        for (int c = 0; c < 16; ++c) e[c] *= inv;
    }
    const int rbase = (lane >> 4) * 4;
    #pragma unroll
    for (int i = 0; i < 4; ++i) {
        const int g = ((m0 + wm) >> 4) + i;
        #pragma unroll
        for (int j = 0; j < 4; ++j) {
            float wsum = e[rbase + 0] * acc[i][j][0] + e[rbase + 1] * acc[i][j][1]
                       + e[rbase + 2] * acc[i][j][2] + e[rbase + 3] * acc[i][j][3];
            wsum += __shfl_xor(wsum, 16, 64);
            wsum += __shfl_xor(wsum, 32, 64);
            if (lane < 16)
                W2h[((long)b * 16 + g) * 256 + n0 + wn + j * 16 + lane] = (_Float16)wsum;
        }
    }
}

// ---------------------------------------------------------------------------
// attn2 (norms fused, R17/R19-validated).
// ---------------------------------------------------------------------------
__global__ __launch_bounds__(256) void attn2_kernel(
    const float* __restrict__ S1, const _Float16* __restrict__ Th,
    const _Float16* __restrict__ wqkvh, const float* __restrict__ wqkv,
    const float* __restrict__ temp, _Float16* __restrict__ MmT)
{
    const int bh = blockIdx.x;
    const int b = bh >> 3, h = bh & 7;
    const int t = threadIdx.x;
    __shared__ float pa[32][36];
    __shared__ float qn[32], kn[32];

    {
        const int r = t >> 3, c4 = (t & 7) * 4;
        const float4 v = *(const float4*)(
            S1 + (long)b * 65536 + (long)(h * 32 + r) * 256 + h * 32 + c4);
        pa[r][c4 + 0] = v.x; pa[r][c4 + 1] = v.y;
        pa[r][c4 + 2] = v.z; pa[r][c4 + 3] = v.w;
    }
    {
        const int r = t >> 2, q = t & 3;
        const long rrow = (r < 32) ? (long)(h * 32 + r) : (long)(256 + h * 32 + (r - 32));
        const _Float16* ta = Th + (long)b * 131072 + rrow * 256 + q * 64;
        const _Float16* wa = wqkvh + rrow * 256 + q * 64;
        float s = 0.f;
        #pragma unroll
        for (int k = 0; k < 64; k += 4) {
            const half4 a = *(const half4*)(ta + k);
            const half4 w = *(const half4*)(wa + k);
            s += (float)a[0] * (float)w[0] + (float)a[1] * (float)w[1]
               + (float)a[2] * (float)w[2] + (float)a[3] * (float)w[3];
        }
        s += __shfl_xor(s, 1, 64);
        s += __shfl_xor(s, 2, 64);
        if (q == 0) {
            const float v = fmaxf(sqrtf(s), 1e-12f);
            if (r < 32) qn[r] = v; else kn[r - 32] = v;
        }
    }
    __syncthreads();

    if (t < 32) {
        const float qin = temp[h] / qn[t];
        float lg[32];
        float mx = -1e30f;
        #pragma unroll
        for (int d = 0; d < 32; ++d) {
            const float l = pa[t][d] * qin / kn[d];
            lg[d] = l;
            mx = fmaxf(mx, l);
        }
        float s = 0.f;
        #pragma unroll
        for (int d = 0; d < 32; ++d) { lg[d] = __expf(lg[d] - mx); s += lg[d]; }
        const float inv = 1.0f / s;
        #pragma unroll
        for (int d = 0; d < 32; ++d) pa[t][d] = lg[d] * inv;
    }
    __syncthreads();

    float accm[32];
    #pragma unroll
    for (int c = 0; c < 32; ++c) accm[c] = 0.f;
    const float* wvp = wqkv + (long)(512 + h * 32) * 256 + t;
    #pragma unroll 4
    for (int d = 0; d < 32; ++d) {
        const float wvv = wvp[(long)d * 256];
        #pragma unroll
        for (int c = 0; c < 32; ++c) accm[c] += pa[c][d] * wvv;
    }
    _Float16* mo = MmT + (long)b * 65536 + (long)t * 256 + h * 32;
    #pragma unroll
    for (int c = 0; c < 32; ++c) mo[c] = (_Float16)accm[c];
}

// ---------------------------------------------------------------------------
// out_fused64 (R21 structure) + X-from-LDS capture: the epilogue's X[c][n]
// patch (c in the M-range = channels) passes through the LDS B-tile at
// k-steps ks1=2*by (rows m0..m0+31) and ks1+1 (m0+32..m0+63). Capture 16 f16
// into registers there (static-indexed x0/x1 arrays) — kills the 32 MB Xh
// global re-read. Values bit-identical (same Xt f16 data).
// ---------------------------------------------------------------------------
__global__ __launch_bounds__(256) void out_fused(
    const _Float16* __restrict__ Ph, const _Float16* __restrict__ Xt,
    const _Float16* __restrict__ W2h, float* __restrict__ out)
{
    __shared__ __align__(16) char smem[20480];   // [buf0 8K][buf1 8K][S2l 4K]
    float (*cst)[64] = (float(*)[64])smem;       // epilogue overlay 8K
    float (*S2l)[64] = (float(*)[64])(smem + 16384);

    // bijective XCD swizzle over grid (64,4,16) = 4096 blocks
    const int hw = blockIdx.x + 64 * blockIdx.y + 256 * blockIdx.z;
    const int f  = (hw & 7) * 512 + (hw >> 3);
    const int bx = f & 63, by = (f >> 6) & 3, bz = f >> 8;

    const int b = bz;
    const int m0 = by * 64, n0 = bx * 64;
    const _Float16* Ab = Ph + (long)b * 65536;
    const _Float16* Bb = Xt + (long)b * 1048576;
    const _Float16* W2b = W2h + (long)b * 4096;
    const int t = threadIdx.x, lane = t & 63, wv = t >> 6;
    const int wm = (wv >> 1) * 32, wn = (wv & 1) * 32;

    const int ks1 = by * 2;          // k-step whose B-cols == epilogue rows hf=0
    half4 x0[2], x1[2];              // captured X patch: [it] for hf=0 / hf=1

    f32x4 acc[2][2] = {};
    f32x4 s2acc[2] = {};

#define OF_STAGE(P, K0) do {                                                     \
        _Float16* Al_ = (_Float16*)(smem + (P) * 8192);                          \
        _Float16* Bl_ = (_Float16*)(smem + (P) * 8192 + 4096);                   \
        {                                                                        \
            const int e_ = t * 8;                                                \
            const int row_ = e_ >> 5, col_ = e_ & 31;                            \
            GLOAD_LDS16(Ab + (long)(m0 + row_) * 256 + (K0) + col_, &Al_[e_]);   \
            GLOAD_LDS16(Bb + (long)(n0 + row_) * 256 + (K0) + col_, &Bl_[e_]);   \
        } } while (0)

    OF_STAGE(0, 0);
    __syncthreads();
    int cur = 0;
    for (int ks = 0; ks < 8; ++ks) {
        if (ks < 7) OF_STAGE(cur ^ 1, (ks + 1) * 32);
        const int k0 = ks * 32;
        const half8 wf = *(const half8*)(W2b + (long)(lane & 15) * 256 + k0 + (lane >> 4) * 8);
        const _Float16* Al = (const _Float16*)(smem + cur * 8192);
        const _Float16* Bl = (const _Float16*)(smem + cur * 8192 + 4096);
        half8 af[2], bf[2];
        #pragma unroll
        for (int ff = 0; ff < 2; ++ff) {
            af[ff] = *(const half8*)&Al[(wm + ff * 16 + (lane & 15)) * 32 + (lane >> 4) * 8];
            bf[ff] = *(const half8*)&Bl[(wn + ff * 16 + (lane & 15)) * 32 + (lane >> 4) * 8];
        }
        #pragma unroll
        for (int i = 0; i < 2; ++i)
            #pragma unroll
            for (int j = 0; j < 2; ++j)
                acc[i][j] = __builtin_amdgcn_mfma_f32_16x16x32_f16(af[i], bf[j], acc[i][j], 0, 0, 0);
        #pragma unroll
        for (int j = 0; j < 2; ++j)
            s2acc[j] = __builtin_amdgcn_mfma_f32_16x16x32_f16(wf, bf[j], s2acc[j], 0, 0, 0);

        // Capture epilogue X-patch from the valid B-tile (before buffer swap).
        // Bl[r*32+cc] = Xt[n0+r][k0+cc] = X[k0+cc][n0+r].
        if (ks == ks1) {
            #pragma unroll
            for (int it = 0; it < 2; ++it)
                #pragma unroll
                for (int q = 0; q < 4; ++q)
                    x0[it][q] = Bl[((t & 15) * 4 + q) * 32 + it * 16 + (t >> 4)];
        } else if (ks == ks1 + 1) {
            #pragma unroll
            for (int it = 0; it < 2; ++it)
                #pragma unroll
                for (int q = 0; q < 4; ++q)
                    x1[it][q] = Bl[((t & 15) * 4 + q) * 32 + it * 16 + (t >> 4)];
        }
        __syncthreads();
        cur ^= 1;
    }
#undef OF_STAGE

    // S2 (16 groups x 64 cols) -> LDS; wm==0 waves (wn 0 and 32) cover cols
    if (wm == 0) {
        #pragma unroll
        for (int j = 0; j < 2; ++j)
            #pragma unroll
            for (int r = 0; r < 4; ++r)
                S2l[(lane >> 4) * 4 + r][wn + j * 16 + (lane & 15)] = s2acc[j][r];
    }

    float* ob = out + (long)b * 1048576;

    #pragma unroll
    for (int hf = 0; hf < 2; ++hf) {
        if (wm == hf * 32) {
            #pragma unroll
            for (int i = 0; i < 2; ++i)
                #pragma unroll
                for (int j = 0; j < 2; ++j)
                    #pragma unroll
                    for (int r = 0; r < 4; ++r)
                        cst[i * 16 + (lane >> 4) * 4 + r][wn + j * 16 + (lane & 15)] = acc[i][j][r];
        }
        __syncthreads();
        #pragma unroll
        for (int it = 0; it < 2; ++it) {
            const int row = it * 16 + (t >> 4);
            const int col = (t & 15) * 4;
            const int c = m0 + hf * 32 + row;
            const float4 v = *(const float4*)&cst[row][col];
            const float4 s2 = *(const float4*)&S2l[c >> 4][col];
            const half4 xv = (hf == 0) ? x0[it] : x1[it];
            f32x4 o;
            o[0] = (float)xv[0] * sigmoidf_(s2.x) + v.x;
            o[1] = (float)xv[1] * sigmoidf_(s2.y) + v.y;
            o[2] = (float)xv[2] * sigmoidf_(s2.z) + v.z;
            o[3] = (float)xv[3] * sigmoidf_(s2.w) + v.w;
            __builtin_nontemporal_store(o, (f32x4*)(ob + (long)c * 4096 + n0 + col));
        }
        __syncthreads();
    }
}

// ---------------------------------------------------------------------------
// Generic 64x64-tile fp32 GEMM (fallback path only).
// ---------------------------------------------------------------------------
template <bool BT, bool EPI>
__global__ __launch_bounds__(256) void gemm64(
    const float* __restrict__ A, const float* __restrict__ B, float* __restrict__ C,
    int M, int N, int K, long sA, long sB, long sC,
    const float* __restrict__ X, const float* __restrict__ WP)
{
    __shared__ float As[32][68];
    __shared__ float Bs[32][68];
    const int b = blockIdx.z;
    const float* Ab = A + (long)b * sA;
    const float* Bb = B + (long)b * sB;
    float* Cb = C + (long)b * sC;
    const int t = threadIdx.x;
    const int tx = t & 15, ty = t >> 4;
    const int m0 = blockIdx.y * 64, n0 = blockIdx.x * 64;

    float acc[4][4] = {};

    for (int k0 = 0; k0 < K; k0 += 32) {
        __syncthreads();
        #pragma unroll
        for (int f0 = 0; f0 < 512; f0 += 256) {
            const int f1 = f0 + t;
            const int row = f1 >> 3, c4 = f1 & 7;
            const float4 v = *(const float4*)(Ab + (long)(m0 + row) * K + k0 + c4 * 4);
            As[c4 * 4 + 0][row] = v.x;
            As[c4 * 4 + 1][row] = v.y;
            As[c4 * 4 + 2][row] = v.z;
            As[c4 * 4 + 3][row] = v.w;
        }
        if (BT) {
            #pragma unroll
            for (int f0 = 0; f0 < 512; f0 += 256) {
                const int f1 = f0 + t;
                const int row = f1 >> 3, c4 = f1 & 7;
                const float4 v = *(const float4*)(Bb + (long)(n0 + row) * K + k0 + c4 * 4);
                Bs[c4 * 4 + 0][row] = v.x;
                Bs[c4 * 4 + 1][row] = v.y;
                Bs[c4 * 4 + 2][row] = v.z;
                Bs[c4 * 4 + 3][row] = v.w;
            }
        } else {
            #pragma unroll
            for (int f0 = 0; f0 < 512; f0 += 256) {
                const int f1 = f0 + t;
                const int kk = f1 >> 4, c4 = f1 & 15;
                *(float4*)&Bs[kk][c4 * 4] =
                    *(const float4*)(Bb + (long)(k0 + kk) * N + n0 + c4 * 4);
            }
        }
        __syncthreads();
        #pragma unroll
        for (int kk = 0; kk < 32; ++kk) {
            const float4 av = *(const float4*)&As[kk][ty * 4];
            const float4 bv = *(const float4*)&Bs[kk][tx * 4];
            const float a0 = av.x, a1 = av.y, a2 = av.z, a3 = av.w;
            const float b0 = bv.x, b1 = bv.y, b2 = bv.z, b3 = bv.w;
            acc[0][0] += a0 * b0; acc[0][1] += a0 * b1; acc[0][2] += a0 * b2; acc[0][3] += a0 * b3;
            acc[1][0] += a1 * b0; acc[1][1] += a1 * b1; acc[1][2] += a1 * b2; acc[1][3] += a1 * b3;
            acc[2][0] += a2 * b0; acc[2][1] += a2 * b1; acc[2][2] += a2 * b2; acc[2][3] += a2 * b3;
            acc[3][0] += a3 * b0; acc[3][1] += a3 * b1; acc[3][2] += a3 * b2; acc[3][3] += a3 * b3;
        }
    }

    if (EPI) {
        #pragma unroll
        for (int i = 0; i < 4; ++i) {
            const int c = m0 + ty * 4 + i;
            const long nidx = n0 + tx * 4;
            const float4 xv = *(const float4*)(X + ((long)b * 256 + c) * 4096 + nidx);
            const float4 wv = *(const float4*)(WP + ((long)b * 16 + (c >> 4)) * 4096 + nidx);
            float4 o;
            o.x = xv.x * sigmoidf_(wv.x) + acc[i][0];
            o.y = xv.y * sigmoidf_(wv.y) + acc[i][1];
            o.z = xv.z * sigmoidf_(wv.z) + acc[i][2];
            o.w = xv.w * sigmoidf_(wv.w) + acc[i][3];
            *(float4*)(Cb + (long)c * N + nidx) = o;
        }
    } else {
        #pragma unroll
        for (int i = 0; i < 4; ++i) {
            const float4 o = make_float4(acc[i][0], acc[i][1], acc[i][2], acc[i][3]);
            *(float4*)(Cb + (long)(m0 + ty * 4 + i) * N + n0 + tx * 4) = o;
        }
    }
}

// ---------------------------------------------------------------------------
// attn (fallback path only).
// ---------------------------------------------------------------------------
__global__ __launch_bounds__(256) void attn_kernel(
    const float* __restrict__ T, const float* __restrict__ wqkv,
    const float* __restrict__ temp, float* __restrict__ Mout, long tStride)
{
    const int bh = blockIdx.x;
    const int b = bh >> 3, h = bh & 7;
    const int t = threadIdx.x;
    __shared__ float Tq[32][260];
    __shared__ float qk[32][33];
    __shared__ float qn[32], kn[32];
    const float* Tb = T + (long)b * tStride;

    for (int f = t; f < 32 * 64; f += 256) {
        const int r = f >> 6, c4 = f & 63;
        *(float4*)&Tq[r][c4 * 4] = *(const float4*)(Tb + (long)(h * 32 + r) * 256 + c4 * 4);
    }
    __syncthreads();

    if (t < 32) {
        float s = 0.f;
        const float* wq = wqkv + (long)(h * 32 + t) * 256;
        #pragma unroll 4
        for (int k = 0; k < 256; k += 4) {
            const float4 a = *(const float4*)&Tq[t][k];
            const float4 w = *(const float4*)(wq + k);
            s += a.x * w.x + a.y * w.y + a.z * w.z + a.w * w.w;
        }
        qn[t] = fmaxf(sqrtf(s), 1e-12f);
    } else if (t < 64) {
        const int d = t - 32;
        float s = 0.f;
        const float* tk = Tb + (long)(256 + h * 32 + d) * 256;
        const float* wk = wqkv + (long)(256 + h * 32 + d) * 256;
        #pragma unroll 4
        for (int k = 0; k < 256; k += 4) {
            const float4 a = *(const float4*)(tk + k);
            const float4 w = *(const float4*)(wk + k);
            s += a.x * w.x + a.y * w.y + a.z * w.z + a.w * w.w;
        }
        kn[d] = fmaxf(sqrtf(s), 1e-12f);
    }

    {
        const int c = t >> 3, d0 = (t & 7) * 4;
        float s0 = 0, s1 = 0, s2 = 0, s3 = 0;
        const float* wk0 = wqkv + (long)(256 + h * 32 + d0) * 256;
        #pragma unroll 4
        for (int k = 0; k < 256; k += 4) {
            const float4 a = *(const float4*)&Tq[c][k];
            const float4 w0 = *(const float4*)(wk0 + k);
            const float4 w1 = *(const float4*)(wk0 + 256 + k);
            const float4 w2 = *(const float4*)(wk0 + 512 + k);
            const float4 w3 = *(const float4*)(wk0 + 768 + k);
            s0 += a.x * w0.x + a.y * w0.y + a.z * w0.z + a.w * w0.w;
            s1 += a.x * w1.x + a.y * w1.y + a.z * w1.z + a.w * w1.w;
            s2 += a.x * w2.x + a.y * w2.y + a.z * w2.z + a.w * w2.w;
            s3 += a.x * w3.x + a.y * w3.y + a.z * w3.z + a.w * w3.w;
        }
        qk[c][d0 + 0] = s0;
        qk[c][d0 + 1] = s1;
        qk[c][d0 + 2] = s2;
        qk[c][d0 + 3] = s3;
    }
    __syncthreads();

    if (t < 32) {
        const float tscale = temp[h];
        const float qin = tscale / qn[t];
        float lg[32];
        float mx = -1e30f;
        #pragma unroll
        for (int d = 0; d < 32; ++d) {
            const float l = qk[t][d] * qin / kn[d];
            lg[d] = l;
            mx = fmaxf(mx, l);
        }
        float s = 0.f;
        #pragma unroll
        for (int d = 0; d < 32; ++d) { lg[d] = __expf(lg[d] - mx); s += lg[d]; }
        const float inv = 1.0f / s;
        #pragma unroll
        for (int d = 0; d < 32; ++d) qk[t][d] = lg[d] * inv;
    }
    __syncthreads();

    float accm[32];
    #pragma unroll
    for (int c = 0; c < 32; ++c) accm[c] = 0.f;
    const float* wvp = wqkv + (long)(512 + h * 32) * 256 + t;
    #pragma unroll 4
    for (int d = 0; d < 32; ++d) {
        const float wvv = wvp[(long)d * 256];
        #pragma unroll
        for (int c = 0; c < 32; ++c) accm[c] += qk[c][d] * wvv;
    }
    float* mo = Mout + (long)b * 256 * 256 + (long)(h * 32) * 256 + t;
    #pragma unroll
    for (int c = 0; c < 32; ++c) mo[(long)c * 256] = accm[c];
}

// ---------------------------------------------------------------------------
// W2 (fallback, fp32)
// ---------------------------------------------------------------------------
__global__ __launch_bounds__(256) void w2_kernel(
    const float* __restrict__ P, const float* __restrict__ gnb, float* __restrict__ W2)
{
    const int b = blockIdx.x, i = threadIdx.x;
    float e[16];
    float mx = -1e30f;
    #pragma unroll
    for (int c = 0; c < 16; ++c) mx = fmaxf(mx, gnb[c]);
    float s = 0.f;
    #pragma unroll
    for (int c = 0; c < 16; ++c) { e[c] = __expf(gnb[c] - mx); s += e[c]; }
    const float inv = 1.0f / s;
    const float* Pb = P + (long)b * 256 * 256 + i;
    #pragma unroll
    for (int g = 0; g < 16; ++g) {
        float acc = 0.f;
        #pragma unroll
        for (int c = 0; c < 16; ++c) acc += e[c] * Pb[(long)(g * 16 + c) * 256];
        W2[((long)b * 16 + g) * 256 + i] = acc * inv;
    }
}

// ---------------------------------------------------------------------------
// WP (fallback path only)
// ---------------------------------------------------------------------------
__global__ __launch_bounds__(256) void wpre_kernel(
    const float* __restrict__ W2, const float* __restrict__ X, float* __restrict__ WP)
{
    __shared__ float w2s[16][260];
    const int b = blockIdx.y;
    const int n = blockIdx.x * 256 + threadIdx.x;
    for (int f = threadIdx.x; f < 16 * 64; f += 256) {
        const int g = f >> 6, c4 = f & 63;
        *(float4*)&w2s[g][c4 * 4] = *(const float4*)(W2 + ((long)b * 16 + g) * 256 + c4 * 4);
    }
    __syncthreads();
    float acc[16] = {};
    const float* xb = X + (long)b * 256 * 4096 + n;
    for (int k = 0; k < 256; ++k) {
        const float xv = xb[(long)k * 4096];
        #pragma unroll
        for (int g = 0; g < 16; ++g) acc[g] += w2s[g][k] * xv;
    }
    #pragma unroll
    for (int g = 0; g < 16; ++g) WP[((long)b * 16 + g) * 4096 + n] = acc[g];
}

// ---------------------------------------------------------------------------
extern "C" void kernel_launch(void* const* d_in, const int* in_sizes, int n_in,
                              void* d_out, int out_size, void* d_ws, size_t ws_size,
                              hipStream_t stream)
{
    const float* x     = (const float*)d_in[0];
    const float* gnb   = (const float*)d_in[4];
    const float* wqkv  = (const float*)d_in[5];
    const float* wproj = (const float*)d_in[6];
    const float* temp  = (const float*)d_in[7];
    float* out = (float*)d_out;

    if (ws_size >= 82051072ULL) {
        // Workspace: [Xh 32M][Xt 32M][S1 4M][pool 10.25M]
        // pool: wqkvh(384K) wprojh(128K) Gh|MmT(2M) Th(4M) Ph(2M) W2h(128K)
        // Gram split-K f16 partials (16 MB) live in d_out (dead until out_fused).
        char* w = (char*)d_ws;
        _Float16* Xh = (_Float16*)w;
        _Float16* Xt = (_Float16*)(w + 33554432);
        float*    S1 = (float*)(w + 67108864);
        char*     pool = w + 71303168;
        _Float16* wqkvh  = (_Float16*)pool;
        _Float16* wprojh = (_Float16*)(pool + 393216);
        _Float16* Gh     = (_Float16*)(pool + 524288);
        _Float16* MmT    = (_Float16*)(pool + 524288);   // overlay: Gh dead after T-gemm
        _Float16* Th     = (_Float16*)(pool + 2621440);
        _Float16* Ph     = (_Float16*)(pool + 6848512);
        _Float16* W2h    = (_Float16*)(pool + 8945664);
        _Float16* pGh    = (_Float16*)d_out;             // scratch, overwritten later

        // 1. X -> Xh + Xt  (+ weight cvt blocks, one launch)
        prep_fused<<<dim3(68, 4, 16), 256, 0, stream>>>(
            x, Xh, Xt, wqkv, wproj, wqkvh, wprojh);
        // 2. symmetric Gram split-K f16 partials into d_out (384 blocks)
        gram_split<<<dim3(3, 128), 256, 0, stream>>>(Xh, pGh);
        // 3. Gh = f16(sum of 8 partials) + fused symmetric mirror
        reduce_mirror<<<dim3(12, 16), 256, 0, stream>>>(pGh, Gh);
        // 4. Th = wqkvh[0:512] @ Gh (BT via G symmetry), f16 out
        mfma_bt<false, true><<<dim3(2, 4, 16), 256, 0, stream>>>(
            wqkvh, Gh, nullptr, Th, 0L, 65536L, 131072L);
        // 5. S1 diag 128-tiles = Tq @ Wk^T, fp32 out
        mfma_bt<true, false><<<dim3(1, 2, 16), 256, 0, stream>>>(
            Th, wqkvh + 65536, S1, nullptr, 131072L, 0L, 65536L);
        // 6. attn2 (norms fused) -> MmT (f16, transposed)
        attn2_kernel<<<128, 256, 0, stream>>>(S1, Th, wqkvh, wqkv, temp, MmT);
        // 7. Ph = wprojh @ Mm (BT via MmT) + fused W2h epilogue
        mfma_pw<<<dim3(2, 2, 16), 256, 0, stream>>>(wprojh, MmT, Ph, gnb, W2h);
        // 8. out = Ph@X + X*sigmoid(W2h@X)  (64x64, X-patch from LDS B-tile)
        out_fused<<<dim3(64, 4, 16), 256, 0, stream>>>(Ph, Xt, W2h, out);
    } else {
        // Fallback: fp32 path (~30 MB workspace)
        float* ws = (float*)d_ws;
        float* G  = ws;
        float* T  = G  + 16L * 65536;
        float* Mm = T  + 16L * 196608;
        float* P  = Mm + 16L * 65536;
        float* W2 = P  + 16L * 65536;
        float* WP = W2 + 16L * 4096;

        gemm64<true, false><<<dim3(4, 4, 16), 256, 0, stream>>>(
            x, x, G, 256, 256, 4096, 1048576L, 1048576L, 65536L, nullptr, nullptr);
        gemm64<false, false><<<dim3(4, 12, 16), 256, 0, stream>>>(
            wqkv, G, T, 768, 256, 256, 0L, 65536L, 196608L, nullptr, nullptr);
        attn_kernel<<<128, 256, 0, stream>>>(T, wqkv, temp, Mm, 196608L);
        gemm64<false, false><<<dim3(4, 4, 16), 256, 0, stream>>>(
            wproj, Mm, P, 256, 256, 256, 0L, 65536L, 65536L, nullptr, nullptr);
        w2_kernel<<<16, 256, 0, stream>>>(P, gnb, W2);
        wpre_kernel<<<dim3(16, 16), 256, 0, stream>>>(W2, x, WP);
        gemm64<false, true><<<dim3(64, 4, 16), 256, 0, stream>>>(
            P, x, out, 256, 4096, 256, 65536L, 1048576L, 1048576L, x, WP);
    }
}

// Round 23
// 109.723 us; speedup vs baseline: 1.0610x; 1.0610x over previous
//
#include <hip/hip_runtime.h>
#include <math.h>

// Problem constants: B=16, C=256, H=W=64, N=4096, GROUPS=16 (cg=16), HEADS=8 (ch=32)
// R23 = byte-exact revert to the best measured configuration (R19, 110.06 us).

__device__ __forceinline__ float sigmoidf_(float v) { return 1.0f / (1.0f + __expf(-v)); }

typedef _Float16 half8 __attribute__((ext_vector_type(8)));
typedef _Float16 half4 __attribute__((ext_vector_type(4)));
typedef float f32x4 __attribute__((ext_vector_type(4)));

#define GLOAD_LDS16(gp, lp)                                                     \
    __builtin_amdgcn_global_load_lds(                                           \
        (const __attribute__((address_space(1))) void*)(gp),                    \
        (__attribute__((address_space(3))) void*)(lp), 16, 0, 0)

// ---------------------------------------------------------------------------
// prep_fused: X (fp32) -> Xh + Xt; blocks with blockIdx.x>=64 convert weights.
// ---------------------------------------------------------------------------
__global__ __launch_bounds__(256) void prep_fused(
    const float* __restrict__ X, _Float16* __restrict__ Xh, _Float16* __restrict__ Xt,
    const float* __restrict__ wqkv, const float* __restrict__ wproj,
    _Float16* __restrict__ wqkvh, _Float16* __restrict__ wprojh)
{
    __shared__ float tl[64][68];
    if (blockIdx.x >= 64) {
        const int blk = (blockIdx.x - 64) * 64 + blockIdx.y * 16 + blockIdx.z;
        if (blk < 192) {
            const long i = ((long)blk * 256 + threadIdx.x) * 4;
            const float4 v = *(const float4*)(wqkv + i);
            half4 h = { (_Float16)v.x, (_Float16)v.y, (_Float16)v.z, (_Float16)v.w };
            *(half4*)(wqkvh + i) = h;
        } else {
            const long i = ((long)(blk - 192) * 256 + threadIdx.x) * 4;
            const float4 v = *(const float4*)(wproj + i);
            half4 h = { (_Float16)v.x, (_Float16)v.y, (_Float16)v.z, (_Float16)v.w };
            *(half4*)(wprojh + i) = h;
        }
        return;
    }
    const int b = blockIdx.z, c0 = blockIdx.y * 64, n0 = blockIdx.x * 64;
    const int t = threadIdx.x;
    const int r0 = t >> 4;
    const int q = (t & 15) * 4;
    const float* Xb = X + ((long)b * 256 + c0) * 4096 + n0;
    _Float16* Xhb = Xh + ((long)b * 256 + c0) * 4096 + n0;
    #pragma unroll
    for (int i = 0; i < 4; ++i) {
        const int r = r0 + i * 16;
        const float4 v = *(const float4*)(Xb + (long)r * 4096 + q);
        tl[r][q + 0] = v.x; tl[r][q + 1] = v.y;
        tl[r][q + 2] = v.z; tl[r][q + 3] = v.w;
        half4 h = { (_Float16)v.x, (_Float16)v.y, (_Float16)v.z, (_Float16)v.w };
        *(half4*)(Xhb + (long)r * 4096 + q) = h;
    }
    __syncthreads();
    const int nn = t >> 2, cc = (t & 3) * 16;
    _Float16* Xtb = Xt + ((long)b * 4096 + n0 + nn) * 256 + c0 + cc;
    half8 o0, o1;
    #pragma unroll
    for (int k = 0; k < 8; ++k) o0[k] = (_Float16)tl[cc + k][nn];
    #pragma unroll
    for (int k = 0; k < 8; ++k) o1[k] = (_Float16)tl[cc + 8 + k][nn];
    *(half8*)(Xtb) = o0;
    *(half8*)(Xtb + 8) = o1;
}

// ---------------------------------------------------------------------------
// Gram split-K, SYMMETRIC, f16 partials: tiles (0,0),(128,128),(0,128) per
// (b,s) -> 384 blocks, XCD-swizzled. pGh (f16) in d_out, slab stride 1048576.
// ---------------------------------------------------------------------------
__global__ __launch_bounds__(256) void gram_split(const _Float16* __restrict__ Xh,
                                                  _Float16* __restrict__ pGh)
{
    __shared__ _Float16 Al[128 * 32];
    __shared__ _Float16 Bl[128 * 32];
    const int hw = blockIdx.x + 3 * blockIdx.y;
    const int f  = (hw & 7) * 48 + (hw >> 3);
    const int tile = f % 3;
    const int bz = f / 3;
    const int b = bz >> 3, s = bz & 7;
    const int m0 = (tile == 1) ? 128 : 0;
    const int n0 = (tile == 0) ? 0 : 128;
    const _Float16* Xb = Xh + (long)b * 256 * 4096;
    const int t = threadIdx.x, lane = t & 63, wv = t >> 6;
    const int wm = (wv >> 1) * 64, wn = (wv & 1) * 64;
    f32x4 acc[4][4] = {};

    const int kbeg = s * 512, kend = kbeg + 512;
    for (int k0 = kbeg; k0 < kend; k0 += 32) {
        __syncthreads();
        #pragma unroll
        for (int r = 0; r < 2; ++r) {
            const int e = (r * 256 + t) * 8;
            const int row = e >> 5, col = e & 31;
            GLOAD_LDS16(Xb + (long)(m0 + row) * 4096 + k0 + col, &Al[e]);
            GLOAD_LDS16(Xb + (long)(n0 + row) * 4096 + k0 + col, &Bl[e]);
        }
        __syncthreads();
        half8 af[4], bf[4];
        #pragma unroll
        for (int ff = 0; ff < 4; ++ff) {
            af[ff] = *(const half8*)&Al[(wm + ff * 16 + (lane & 15)) * 32 + (lane >> 4) * 8];
            bf[ff] = *(const half8*)&Bl[(wn + ff * 16 + (lane & 15)) * 32 + (lane >> 4) * 8];
        }
        #pragma unroll
        for (int i = 0; i < 4; ++i)
            #pragma unroll
            for (int j = 0; j < 4; ++j)
                acc[i][j] = __builtin_amdgcn_mfma_f32_16x16x32_f16(af[i], bf[j], acc[i][j], 0, 0, 0);
    }
    _Float16* pGb = pGh + (long)s * 1048576 + (long)b * 65536;
    #pragma unroll
    for (int i = 0; i < 4; ++i)
        #pragma unroll
        for (int j = 0; j < 4; ++j) {
            const int row = m0 + wm + i * 16 + (lane >> 4) * 4;
            const int col = n0 + wn + j * 16 + (lane & 15);
            _Float16* gp = pGb + (long)row * 256 + col;
            #pragma unroll
            for (int r = 0; r < 4; ++r) gp[(long)r * 256] = (_Float16)acc[i][j][r];
        }
}

// ---------------------------------------------------------------------------
// reduce_mirror: Gh = f16(sum_s pGh[s]) over the 12 computed 64x64 tiles per
// batch; upper-right tiles also LDS-transpose into the mirrored lower-left.
// ---------------------------------------------------------------------------
__global__ __launch_bounds__(256) void reduce_mirror(const _Float16* __restrict__ pGh,
                                                     _Float16* __restrict__ Gh)
{
    __shared__ _Float16 tl[64][72];
    const int idx = blockIdx.x, b = blockIdx.y;
    int ty, tx;
    bool mirror = false;
    if (idx < 4)       { ty = idx >> 1;        tx = idx & 1; }
    else if (idx < 8)  { ty = 2 + ((idx - 4) >> 1); tx = 2 + ((idx - 4) & 1); }
    else               { ty = (idx - 8) >> 1;  tx = 2 + ((idx - 8) & 1); mirror = true; }
    const int r0 = ty * 64, c0 = tx * 64;
    const int t = threadIdx.x;
    const int ii = t >> 2, jj = (t & 3) * 16;

    const _Float16* pGb = pGh + (long)b * 65536 + (long)(r0 + ii) * 256 + c0 + jj;
    _Float16* Gb = Gh + (long)b * 65536;
    _Float16 hv[16];
    #pragma unroll
    for (int q = 0; q < 4; ++q) {
        f32x4 s = {};
        #pragma unroll
        for (int k = 0; k < 8; ++k) {
            const half4 v = *(const half4*)(pGb + (long)k * 1048576 + q * 4);
            s[0] += (float)v[0]; s[1] += (float)v[1];
            s[2] += (float)v[2]; s[3] += (float)v[3];
        }
        hv[q * 4 + 0] = (_Float16)s[0]; hv[q * 4 + 1] = (_Float16)s[1];
        hv[q * 4 + 2] = (_Float16)s[2]; hv[q * 4 + 3] = (_Float16)s[3];
    }
    *(half8*)(Gb + (long)(r0 + ii) * 256 + c0 + jj)     = *(half8*)&hv[0];
    *(half8*)(Gb + (long)(r0 + ii) * 256 + c0 + jj + 8) = *(half8*)&hv[8];

    if (mirror) {
        #pragma unroll
        for (int k = 0; k < 16; ++k) tl[ii][jj + k] = hv[k];
        __syncthreads();
        half8 o0, o1;
        #pragma unroll
        for (int k = 0; k < 8; ++k) o0[k] = tl[jj + k][ii];
        #pragma unroll
        for (int k = 0; k < 8; ++k) o1[k] = tl[jj + 8 + k][ii];
        *(half8*)(Gb + (long)(c0 + ii) * 256 + r0 + jj)     = o0;
        *(half8*)(Gb + (long)(c0 + ii) * 256 + r0 + jj + 8) = o1;
    }
}

// ---------------------------------------------------------------------------
// mfma_bt: C[m][n] = sum_k A[m][k]*B[n][k], K=256 fixed, N-ld 256.
// DIAG: n0=m0. F16OUT: write f16, else fp32.
// ---------------------------------------------------------------------------
template <bool DIAG, bool F16OUT>
__global__ __launch_bounds__(256) void mfma_bt(
    const _Float16* __restrict__ A, const _Float16* __restrict__ B,
    float* __restrict__ Cf, _Float16* __restrict__ Ch,
    long sA, long sB, long sC)
{
    __shared__ _Float16 Al[128 * 32];
    __shared__ _Float16 Bl[128 * 32];
    const int b = blockIdx.z;
    const int m0 = blockIdx.y * 128;
    const int n0 = DIAG ? m0 : blockIdx.x * 128;
    const _Float16* Ab = A + (long)b * sA;
    const _Float16* Bb = B + (long)b * sB;
    const int t = threadIdx.x, lane = t & 63, wv = t >> 6;
    const int wm = (wv >> 1) * 64, wn = (wv & 1) * 64;
    f32x4 acc[4][4] = {};

    for (int k0 = 0; k0 < 256; k0 += 32) {
        __syncthreads();
        #pragma unroll
        for (int r = 0; r < 2; ++r) {
            const int e = (r * 256 + t) * 8;
            const int row = e >> 5, col = e & 31;
            GLOAD_LDS16(Ab + (long)(m0 + row) * 256 + k0 + col, &Al[e]);
            GLOAD_LDS16(Bb + (long)(n0 + row) * 256 + k0 + col, &Bl[e]);
        }
        __syncthreads();
        half8 af[4], bf[4];
        #pragma unroll
        for (int ff = 0; ff < 4; ++ff) {
            af[ff] = *(const half8*)&Al[(wm + ff * 16 + (lane & 15)) * 32 + (lane >> 4) * 8];
            bf[ff] = *(const half8*)&Bl[(wn + ff * 16 + (lane & 15)) * 32 + (lane >> 4) * 8];
        }
        #pragma unroll
        for (int i = 0; i < 4; ++i)
            #pragma unroll
            for (int j = 0; j < 4; ++j)
                acc[i][j] = __builtin_amdgcn_mfma_f32_16x16x32_f16(af[i], bf[j], acc[i][j], 0, 0, 0);
    }
    #pragma unroll
    for (int i = 0; i < 4; ++i)
        #pragma unroll
        for (int j = 0; j < 4; ++j) {
            const int row = m0 + wm + i * 16 + (lane >> 4) * 4;
            const int col = n0 + wn + j * 16 + (lane & 15);
            #pragma unroll
            for (int r = 0; r < 4; ++r) {
                if (F16OUT)
                    Ch[(long)b * sC + (long)(row + r) * 256 + col] = (_Float16)acc[i][j][r];
                else
                    Cf[(long)b * sC + (long)(row + r) * 256 + col] = acc[i][j][r];
            }
        }
}

// ---------------------------------------------------------------------------
// mfma_pw: Ph = wprojh @ Mm (BT via MmT), f16 out, + fused W2h epilogue.
// ---------------------------------------------------------------------------
__global__ __launch_bounds__(256) void mfma_pw(
    const _Float16* __restrict__ A, const _Float16* __restrict__ B,
    _Float16* __restrict__ Ch, const float* __restrict__ gnb,
    _Float16* __restrict__ W2h)
{
    __shared__ _Float16 Al[128 * 32];
    __shared__ _Float16 Bl[128 * 32];
    const int b = blockIdx.z;
    const int m0 = blockIdx.y * 128;
    const int n0 = blockIdx.x * 128;
    const _Float16* Ab = A;
    const _Float16* Bb = B + (long)b * 65536;
    const int t = threadIdx.x, lane = t & 63, wv = t >> 6;
    const int wm = (wv >> 1) * 64, wn = (wv & 1) * 64;
    f32x4 acc[4][4] = {};

    for (int k0 = 0; k0 < 256; k0 += 32) {
        __syncthreads();
        #pragma unroll
        for (int r = 0; r < 2; ++r) {
            const int e = (r * 256 + t) * 8;
            const int row = e >> 5, col = e & 31;
            GLOAD_LDS16(Ab + (long)(m0 + row) * 256 + k0 + col, &Al[e]);
            GLOAD_LDS16(Bb + (long)(n0 + row) * 256 + k0 + col, &Bl[e]);
        }
        __syncthreads();
        half8 af[4], bf[4];
        #pragma unroll
        for (int ff = 0; ff < 4; ++ff) {
            af[ff] = *(const half8*)&Al[(wm + ff * 16 + (lane & 15)) * 32 + (lane >> 4) * 8];
            bf[ff] = *(const half8*)&Bl[(wn + ff * 16 + (lane & 15)) * 32 + (lane >> 4) * 8];
        }
        #pragma unroll
        for (int i = 0; i < 4; ++i)
            #pragma unroll
            for (int j = 0; j < 4; ++j)
                acc[i][j] = __builtin_amdgcn_mfma_f32_16x16x32_f16(af[i], bf[j], acc[i][j], 0, 0, 0);
    }
    #pragma unroll
    for (int i = 0; i < 4; ++i)
        #pragma unroll
        for (int j = 0; j < 4; ++j) {
            const int row = m0 + wm + i * 16 + (lane >> 4) * 4;
            const int col = n0 + wn + j * 16 + (lane & 15);
            #pragma unroll
            for (int r = 0; r < 4; ++r)
                Ch[(long)b * 65536 + (long)(row + r) * 256 + col] = (_Float16)acc[i][j][r];
        }
    float e[16];
    {
        float mx = -1e30f;
        #pragma unroll
        for (int c = 0; c < 16; ++c) mx = fmaxf(mx, gnb[c]);
        float s = 0.f;
        #pragma unroll
        for (int c = 0; c < 16; ++c) { e[c] = __expf(gnb[c] - mx); s += e[c]; }
        const float inv = 1.0f / s;
        #pragma unroll
        for (int c = 0; c < 16; ++c) e[c] *= inv;
    }
    const int rbase = (lane >> 4) * 4;
    #pragma unroll
    for (int i = 0; i < 4; ++i) {
        const int g = ((m0 + wm) >> 4) + i;
        #pragma unroll
        for (int j = 0; j < 4; ++j) {
            float wsum = e[rbase + 0] * acc[i][j][0] + e[rbase + 1] * acc[i][j][1]
                       + e[rbase + 2] * acc[i][j][2] + e[rbase + 3] * acc[i][j][3];
            wsum += __shfl_xor(wsum, 16, 64);
            wsum += __shfl_xor(wsum, 32, 64);
            if (lane < 16)
                W2h[((long)b * 16 + g) * 256 + n0 + wn + j * 16 + lane] = (_Float16)wsum;
        }
    }
}

// ---------------------------------------------------------------------------
// attn2 (norms fused): per (b,h): qn/kn from Th.wqkvh dots; softmax; @Wv -> MmT.
// ---------------------------------------------------------------------------
__global__ __launch_bounds__(256) void attn2_kernel(
    const float* __restrict__ S1, const _Float16* __restrict__ Th,
    const _Float16* __restrict__ wqkvh, const float* __restrict__ wqkv,
    const float* __restrict__ temp, _Float16* __restrict__ MmT)
{
    const int bh = blockIdx.x;
    const int b = bh >> 3, h = bh & 7;
    const int t = threadIdx.x;
    __shared__ float pa[32][36];
    __shared__ float qn[32], kn[32];

    {
        const int r = t >> 3, c4 = (t & 7) * 4;
        const float4 v = *(const float4*)(
            S1 + (long)b * 65536 + (long)(h * 32 + r) * 256 + h * 32 + c4);
        pa[r][c4 + 0] = v.x; pa[r][c4 + 1] = v.y;
        pa[r][c4 + 2] = v.z; pa[r][c4 + 3] = v.w;
    }
    {
        const int r = t >> 2, q = t & 3;
        const long rrow = (r < 32) ? (long)(h * 32 + r) : (long)(256 + h * 32 + (r - 32));
        const _Float16* ta = Th + (long)b * 131072 + rrow * 256 + q * 64;
        const _Float16* wa = wqkvh + rrow * 256 + q * 64;
        float s = 0.f;
        #pragma unroll
        for (int k = 0; k < 64; k += 4) {
            const half4 a = *(const half4*)(ta + k);
            const half4 w = *(const half4*)(wa + k);
            s += (float)a[0] * (float)w[0] + (float)a[1] * (float)w[1]
               + (float)a[2] * (float)w[2] + (float)a[3] * (float)w[3];
        }
        s += __shfl_xor(s, 1, 64);
        s += __shfl_xor(s, 2, 64);
        if (q == 0) {
            const float v = fmaxf(sqrtf(s), 1e-12f);
            if (r < 32) qn[r] = v; else kn[r - 32] = v;
        }
    }
    __syncthreads();

    if (t < 32) {
        const float qin = temp[h] / qn[t];
        float lg[32];
        float mx = -1e30f;
        #pragma unroll
        for (int d = 0; d < 32; ++d) {
            const float l = pa[t][d] * qin / kn[d];
            lg[d] = l;
            mx = fmaxf(mx, l);
        }
        float s = 0.f;
        #pragma unroll
        for (int d = 0; d < 32; ++d) { lg[d] = __expf(lg[d] - mx); s += lg[d]; }
        const float inv = 1.0f / s;
        #pragma unroll
        for (int d = 0; d < 32; ++d) pa[t][d] = lg[d] * inv;
    }
    __syncthreads();

    float accm[32];
    #pragma unroll
    for (int c = 0; c < 32; ++c) accm[c] = 0.f;
    const float* wvp = wqkv + (long)(512 + h * 32) * 256 + t;
    #pragma unroll 4
    for (int d = 0; d < 32; ++d) {
        const float wvv = wvp[(long)d * 256];
        #pragma unroll
        for (int c = 0; c < 32; ++c) accm[c] += pa[c][d] * wvv;
    }
    _Float16* mo = MmT + (long)b * 65536 + (long)t * 256 + h * 32;
    #pragma unroll
    for (int c = 0; c < 32; ++c) mo[c] = (_Float16)accm[c];
}

// ---------------------------------------------------------------------------
// out_fused (R19-validated best): 128x128 tiles, dbuf K-loop, fused S2 gate,
// coalesced LDS epilogue, T1 XCD swizzle, nt stores. LDS 40960 B.
// ---------------------------------------------------------------------------
__global__ __launch_bounds__(256) void out_fused(
    const _Float16* __restrict__ Ph, const _Float16* __restrict__ Xt,
    const _Float16* __restrict__ Xh, const _Float16* __restrict__ W2h,
    float* __restrict__ out)
{
    __shared__ __align__(16) char smem[40960];
    float (*cst)[128] = (float(*)[128])smem;
    float (*S2l)[128] = (float(*)[128])(smem + 32768);

    const int hw = blockIdx.x + 32 * blockIdx.y + 64 * blockIdx.z;
    const int f  = (hw & 7) * 128 + (hw >> 3);
    const int bx = f & 31, by = (f >> 5) & 1, bz = f >> 6;

    const int b = bz;
    const int m0 = by * 128, n0 = bx * 128;
    const _Float16* Ab = Ph + (long)b * 65536;
    const _Float16* Bb = Xt + (long)b * 1048576;
    const _Float16* W2b = W2h + (long)b * 4096;
    const int t = threadIdx.x, lane = t & 63, wv = t >> 6;
    const int wm = (wv >> 1) * 64, wn = (wv & 1) * 64;

    f32x4 acc[4][4] = {};
    f32x4 s2acc[4] = {};

#define OF_STAGE(P, K0) do {                                                     \
        _Float16* Al_ = (_Float16*)(smem + (P) * 16384);                         \
        _Float16* Bl_ = (_Float16*)(smem + (P) * 16384 + 8192);                  \
        _Pragma("unroll")                                                        \
        for (int r_ = 0; r_ < 2; ++r_) {                                         \
            const int e_ = (r_ * 256 + t) * 8;                                   \
            const int row_ = e_ >> 5, col_ = e_ & 31;                            \
            GLOAD_LDS16(Ab + (long)(m0 + row_) * 256 + (K0) + col_, &Al_[e_]);   \
            GLOAD_LDS16(Bb + (long)(n0 + row_) * 256 + (K0) + col_, &Bl_[e_]);   \
        } } while (0)

    OF_STAGE(0, 0);
    __syncthreads();
    int cur = 0;
    for (int ks = 0; ks < 8; ++ks) {
        if (ks < 7) OF_STAGE(cur ^ 1, (ks + 1) * 32);
        const int k0 = ks * 32;
        const half8 wf = *(const half8*)(W2b + (long)(lane & 15) * 256 + k0 + (lane >> 4) * 8);
        const _Float16* Al = (const _Float16*)(smem + cur * 16384);
        const _Float16* Bl = (const _Float16*)(smem + cur * 16384 + 8192);
        half8 af[4], bf[4];
        #pragma unroll
        for (int ff = 0; ff < 4; ++ff) {
            af[ff] = *(const half8*)&Al[(wm + ff * 16 + (lane & 15)) * 32 + (lane >> 4) * 8];
            bf[ff] = *(const half8*)&Bl[(wn + ff * 16 + (lane & 15)) * 32 + (lane >> 4) * 8];
        }
        #pragma unroll
        for (int i = 0; i < 4; ++i)
            #pragma unroll
            for (int j = 0; j < 4; ++j)
                acc[i][j] = __builtin_amdgcn_mfma_f32_16x16x32_f16(af[i], bf[j], acc[i][j], 0, 0, 0);
        #pragma unroll
        for (int j = 0; j < 4; ++j)
            s2acc[j] = __builtin_amdgcn_mfma_f32_16x16x32_f16(wf, bf[j], s2acc[j], 0, 0, 0);
        __syncthreads();
        cur ^= 1;
    }
#undef OF_STAGE

    if (wm == 0) {
        #pragma unroll
        for (int j = 0; j < 4; ++j)
            #pragma unroll
            for (int r = 0; r < 4; ++r)
                S2l[(lane >> 4) * 4 + r][wn + j * 16 + (lane & 15)] = s2acc[j][r];
    }

    const _Float16* Xhb = Xh + (long)b * 1048576;
    float* ob = out + (long)b * 1048576;

    #pragma unroll
    for (int hf = 0; hf < 2; ++hf) {
        if (wm == hf * 64) {
            #pragma unroll
            for (int i = 0; i < 4; ++i)
                #pragma unroll
                for (int j = 0; j < 4; ++j)
                    #pragma unroll
                    for (int r = 0; r < 4; ++r)
                        cst[i * 16 + (lane >> 4) * 4 + r][wn + j * 16 + (lane & 15)] = acc[i][j][r];
        }
        __syncthreads();
        #pragma unroll
        for (int it = 0; it < 8; ++it) {
            const int row = it * 8 + (t >> 5);
            const int col = (t & 31) * 4;
            const int c = m0 + hf * 64 + row;
            const float4 v = *(const float4*)&cst[row][col];
            const float4 s2 = *(const float4*)&S2l[c >> 4][col];
            const half4 xv = *(const half4*)(Xhb + (long)c * 4096 + n0 + col);
            f32x4 o;
            o[0] = (float)xv[0] * sigmoidf_(s2.x) + v.x;
            o[1] = (float)xv[1] * sigmoidf_(s2.y) + v.y;
            o[2] = (float)xv[2] * sigmoidf_(s2.z) + v.z;
            o[3] = (float)xv[3] * sigmoidf_(s2.w) + v.w;
            __builtin_nontemporal_store(o, (f32x4*)(ob + (long)c * 4096 + n0 + col));
        }
        __syncthreads();
    }
}

// ---------------------------------------------------------------------------
// Generic 64x64-tile fp32 GEMM (fallback path only).
// ---------------------------------------------------------------------------
template <bool BT, bool EPI>
__global__ __launch_bounds__(256) void gemm64(
    const float* __restrict__ A, const float* __restrict__ B, float* __restrict__ C,
    int M, int N, int K, long sA, long sB, long sC,
    const float* __restrict__ X, const float* __restrict__ WP)
{
    __shared__ float As[32][68];
    __shared__ float Bs[32][68];
    const int b = blockIdx.z;
    const float* Ab = A + (long)b * sA;
    const float* Bb = B + (long)b * sB;
    float* Cb = C + (long)b * sC;
    const int t = threadIdx.x;
    const int tx = t & 15, ty = t >> 4;
    const int m0 = blockIdx.y * 64, n0 = blockIdx.x * 64;

    float acc[4][4] = {};

    for (int k0 = 0; k0 < K; k0 += 32) {
        __syncthreads();
        #pragma unroll
        for (int f0 = 0; f0 < 512; f0 += 256) {
            const int f1 = f0 + t;
            const int row = f1 >> 3, c4 = f1 & 7;
            const float4 v = *(const float4*)(Ab + (long)(m0 + row) * K + k0 + c4 * 4);
            As[c4 * 4 + 0][row] = v.x;
            As[c4 * 4 + 1][row] = v.y;
            As[c4 * 4 + 2][row] = v.z;
            As[c4 * 4 + 3][row] = v.w;
        }
        if (BT) {
            #pragma unroll
            for (int f0 = 0; f0 < 512; f0 += 256) {
                const int f1 = f0 + t;
                const int row = f1 >> 3, c4 = f1 & 7;
                const float4 v = *(const float4*)(Bb + (long)(n0 + row) * K + k0 + c4 * 4);
                Bs[c4 * 4 + 0][row] = v.x;
                Bs[c4 * 4 + 1][row] = v.y;
                Bs[c4 * 4 + 2][row] = v.z;
                Bs[c4 * 4 + 3][row] = v.w;
            }
        } else {
            #pragma unroll
            for (int f0 = 0; f0 < 512; f0 += 256) {
                const int f1 = f0 + t;
                const int kk = f1 >> 4, c4 = f1 & 15;
                *(float4*)&Bs[kk][c4 * 4] =
                    *(const float4*)(Bb + (long)(k0 + kk) * N + n0 + c4 * 4);
            }
        }
        __syncthreads();
        #pragma unroll
        for (int kk = 0; kk < 32; ++kk) {
            const float4 av = *(const float4*)&As[kk][ty * 4];
            const float4 bv = *(const float4*)&Bs[kk][tx * 4];
            const float a0 = av.x, a1 = av.y, a2 = av.z, a3 = av.w;
            const float b0 = bv.x, b1 = bv.y, b2 = bv.z, b3 = bv.w;
            acc[0][0] += a0 * b0; acc[0][1] += a0 * b1; acc[0][2] += a0 * b2; acc[0][3] += a0 * b3;
            acc[1][0] += a1 * b0; acc[1][1] += a1 * b1; acc[1][2] += a1 * b2; acc[1][3] += a1 * b3;
            acc[2][0] += a2 * b0; acc[2][1] += a2 * b1; acc[2][2] += a2 * b2; acc[2][3] += a2 * b3;
            acc[3][0] += a3 * b0; acc[3][1] += a3 * b1; acc[3][2] += a3 * b2; acc[3][3] += a3 * b3;
        }
    }

    if (EPI) {
        #pragma unroll
        for (int i = 0; i < 4; ++i) {
            const int c = m0 + ty * 4 + i;
            const long nidx = n0 + tx * 4;
            const float4 xv = *(const float4*)(X + ((long)b * 256 + c) * 4096 + nidx);
            const float4 wv = *(const float4*)(WP + ((long)b * 16 + (c >> 4)) * 4096 + nidx);
            float4 o;
            o.x = xv.x * sigmoidf_(wv.x) + acc[i][0];
            o.y = xv.y * sigmoidf_(wv.y) + acc[i][1];
            o.z = xv.z * sigmoidf_(wv.z) + acc[i][2];
            o.w = xv.w * sigmoidf_(wv.w) + acc[i][3];
            *(float4*)(Cb + (long)c * N + nidx) = o;
        }
    } else {
        #pragma unroll
        for (int i = 0; i < 4; ++i) {
            const float4 o = make_float4(acc[i][0], acc[i][1], acc[i][2], acc[i][3]);
            *(float4*)(Cb + (long)(m0 + ty * 4 + i) * N + n0 + tx * 4) = o;
        }
    }
}

// ---------------------------------------------------------------------------
// attn (fallback path only).
// ---------------------------------------------------------------------------
__global__ __launch_bounds__(256) void attn_kernel(
    const float* __restrict__ T, const float* __restrict__ wqkv,
    const float* __restrict__ temp, float* __restrict__ Mout, long tStride)
{
    const int bh = blockIdx.x;
    const int b = bh >> 3, h = bh & 7;
    const int t = threadIdx.x;
    __shared__ float Tq[32][260];
    __shared__ float qk[32][33];
    __shared__ float qn[32], kn[32];
    const float* Tb = T + (long)b * tStride;

    for (int f = t; f < 32 * 64; f += 256) {
        const int r = f >> 6, c4 = f & 63;
        *(float4*)&Tq[r][c4 * 4] = *(const float4*)(Tb + (long)(h * 32 + r) * 256 + c4 * 4);
    }
    __syncthreads();

    if (t < 32) {
        float s = 0.f;
        const float* wq = wqkv + (long)(h * 32 + t) * 256;
        #pragma unroll 4
        for (int k = 0; k < 256; k += 4) {
            const float4 a = *(const float4*)&Tq[t][k];
            const float4 w = *(const float4*)(wq + k);
            s += a.x * w.x + a.y * w.y + a.z * w.z + a.w * w.w;
        }
        qn[t] = fmaxf(sqrtf(s), 1e-12f);
    } else if (t < 64) {
        const int d = t - 32;
        float s = 0.f;
        const float* tk = Tb + (long)(256 + h * 32 + d) * 256;
        const float* wk = wqkv + (long)(256 + h * 32 + d) * 256;
        #pragma unroll 4
        for (int k = 0; k < 256; k += 4) {
            const float4 a = *(const float4*)(tk + k);
            const float4 w = *(const float4*)(wk + k);
            s += a.x * w.x + a.y * w.y + a.z * w.z + a.w * w.w;
        }
        kn[d] = fmaxf(sqrtf(s), 1e-12f);
    }

    {
        const int c = t >> 3, d0 = (t & 7) * 4;
        float s0 = 0, s1 = 0, s2 = 0, s3 = 0;
        const float* wk0 = wqkv + (long)(256 + h * 32 + d0) * 256;
        #pragma unroll 4
        for (int k = 0; k < 256; k += 4) {
            const float4 a = *(const float4*)&Tq[c][k];
            const float4 w0 = *(const float4*)(wk0 + k);
            const float4 w1 = *(const float4*)(wk0 + 256 + k);
            const float4 w2 = *(const float4*)(wk0 + 512 + k);
            const float4 w3 = *(const float4*)(wk0 + 768 + k);
            s0 += a.x * w0.x + a.y * w0.y + a.z * w0.z + a.w * w0.w;
            s1 += a.x * w1.x + a.y * w1.y + a.z * w1.z + a.w * w1.w;
            s2 += a.x * w2.x + a.y * w2.y + a.z * w2.z + a.w * w2.w;
            s3 += a.x * w3.x + a.y * w3.y + a.z * w3.z + a.w * w3.w;
        }
        qk[c][d0 + 0] = s0;
        qk[c][d0 + 1] = s1;
        qk[c][d0 + 2] = s2;
        qk[c][d0 + 3] = s3;
    }
    __syncthreads();

    if (t < 32) {
        const float tscale = temp[h];
        const float qin = tscale / qn[t];
        float lg[32];
        float mx = -1e30f;
        #pragma unroll
        for (int d = 0; d < 32; ++d) {
            const float l = qk[t][d] * qin / kn[d];
            lg[d] = l;
            mx = fmaxf(mx, l);
        }
        float s = 0.f;
        #pragma unroll
        for (int d = 0; d < 32; ++d) { lg[d] = __expf(lg[d] - mx); s += lg[d]; }
        const float inv = 1.0f / s;
        #pragma unroll
        for (int d = 0; d < 32; ++d) qk[t][d] = lg[d] * inv;
    }
    __syncthreads();

    float accm[32];
    #pragma unroll
    for (int c = 0; c < 32; ++c) accm[c] = 0.f;
    const float* wvp = wqkv + (long)(512 + h * 32) * 256 + t;
    #pragma unroll 4
    for (int d = 0; d < 32; ++d) {
        const float wvv = wvp[(long)d * 256];
        #pragma unroll
        for (int c = 0; c < 32; ++c) accm[c] += qk[c][d] * wvv;
    }
    float* mo = Mout + (long)b * 256 * 256 + (long)(h * 32) * 256 + t;
    #pragma unroll
    for (int c = 0; c < 32; ++c) mo[(long)c * 256] = accm[c];
}

// ---------------------------------------------------------------------------
// W2 (fallback, fp32)
// ---------------------------------------------------------------------------
__global__ __launch_bounds__(256) void w2_kernel(
    const float* __restrict__ P, const float* __restrict__ gnb, float* __restrict__ W2)
{
    const int b = blockIdx.x, i = threadIdx.x;
    float e[16];
    float mx = -1e30f;
    #pragma unroll
    for (int c = 0; c < 16; ++c) mx = fmaxf(mx, gnb[c]);
    float s = 0.f;
    #pragma unroll
    for (int c = 0; c < 16; ++c) { e[c] = __expf(gnb[c] - mx); s += e[c]; }
    const float inv = 1.0f / s;
    const float* Pb = P + (long)b * 256 * 256 + i;
    #pragma unroll
    for (int g = 0; g < 16; ++g) {
        float acc = 0.f;
        #pragma unroll
        for (int c = 0; c < 16; ++c) acc += e[c] * Pb[(long)(g * 16 + c) * 256];
        W2[((long)b * 16 + g) * 256 + i] = acc * inv;
    }
}

// ---------------------------------------------------------------------------
// WP (fallback path only)
// ---------------------------------------------------------------------------
__global__ __launch_bounds__(256) void wpre_kernel(
    const float* __restrict__ W2, const float* __restrict__ X, float* __restrict__ WP)
{
    __shared__ float w2s[16][260];
    const int b = blockIdx.y;
    const int n = blockIdx.x * 256 + threadIdx.x;
    for (int f = threadIdx.x; f < 16 * 64; f += 256) {
        const int g = f >> 6, c4 = f & 63;
        *(float4*)&w2s[g][c4 * 4] = *(const float4*)(W2 + ((long)b * 16 + g) * 256 + c4 * 4);
    }
    __syncthreads();
    float acc[16] = {};
    const float* xb = X + (long)b * 256 * 4096 + n;
    for (int k = 0; k < 256; ++k) {
        const float xv = xb[(long)k * 4096];
        #pragma unroll
        for (int g = 0; g < 16; ++g) acc[g] += w2s[g][k] * xv;
    }
    #pragma unroll
    for (int g = 0; g < 16; ++g) WP[((long)b * 16 + g) * 4096 + n] = acc[g];
}

// ---------------------------------------------------------------------------
extern "C" void kernel_launch(void* const* d_in, const int* in_sizes, int n_in,
                              void* d_out, int out_size, void* d_ws, size_t ws_size,
                              hipStream_t stream)
{
    const float* x     = (const float*)d_in[0];
    const float* gnb   = (const float*)d_in[4];
    const float* wqkv  = (const float*)d_in[5];
    const float* wproj = (const float*)d_in[6];
    const float* temp  = (const float*)d_in[7];
    float* out = (float*)d_out;

    if (ws_size >= 82051072ULL) {
        // Workspace: [Xh 32M][Xt 32M][S1 4M][pool 10.25M]
        // pool: wqkvh(384K) wprojh(128K) Gh|MmT(2M) Th(4M) Ph(2M) W2h(128K)
        // Gram split-K f16 partials (16 MB) live in d_out (dead until out_fused).
        char* w = (char*)d_ws;
        _Float16* Xh = (_Float16*)w;
        _Float16* Xt = (_Float16*)(w + 33554432);
        float*    S1 = (float*)(w + 67108864);
        char*     pool = w + 71303168;
        _Float16* wqkvh  = (_Float16*)pool;
        _Float16* wprojh = (_Float16*)(pool + 393216);
        _Float16* Gh     = (_Float16*)(pool + 524288);
        _Float16* MmT    = (_Float16*)(pool + 524288);   // overlay: Gh dead after T-gemm
        _Float16* Th     = (_Float16*)(pool + 2621440);
        _Float16* Ph     = (_Float16*)(pool + 6848512);
        _Float16* W2h    = (_Float16*)(pool + 8945664);
        _Float16* pGh    = (_Float16*)d_out;             // scratch, overwritten later

        // 1. X -> Xh + Xt  (+ weight cvt blocks, one launch)
        prep_fused<<<dim3(68, 4, 16), 256, 0, stream>>>(
            x, Xh, Xt, wqkv, wproj, wqkvh, wprojh);
        // 2. symmetric Gram split-K f16 partials into d_out (384 blocks)
        gram_split<<<dim3(3, 128), 256, 0, stream>>>(Xh, pGh);
        // 3. Gh = f16(sum of 8 partials) + fused symmetric mirror
        reduce_mirror<<<dim3(12, 16), 256, 0, stream>>>(pGh, Gh);
        // 4. Th = wqkvh[0:512] @ Gh (BT via G symmetry), f16 out
        mfma_bt<false, true><<<dim3(2, 4, 16), 256, 0, stream>>>(
            wqkvh, Gh, nullptr, Th, 0L, 65536L, 131072L);
        // 5. S1 diag 128-tiles = Tq @ Wk^T, fp32 out
        mfma_bt<true, false><<<dim3(1, 2, 16), 256, 0, stream>>>(
            Th, wqkvh + 65536, S1, nullptr, 131072L, 0L, 65536L);
        // 6. attn2 (norms fused) -> MmT (f16, transposed)
        attn2_kernel<<<128, 256, 0, stream>>>(S1, Th, wqkvh, wqkv, temp, MmT);
        // 7. Ph = wprojh @ Mm (BT via MmT) + fused W2h epilogue
        mfma_pw<<<dim3(2, 2, 16), 256, 0, stream>>>(wprojh, MmT, Ph, gnb, W2h);
        // 8. out = Ph@X + Xh*sigmoid(W2h@X)  (nt stores)
        out_fused<<<dim3(32, 2, 16), 256, 0, stream>>>(Ph, Xt, Xh, W2h, out);
    } else {
        // Fallback: fp32 path (~30 MB workspace)
        float* ws = (float*)d_ws;
        float* G  = ws;
        float* T  = G  + 16L * 65536;
        float* Mm = T  + 16L * 196608;
        float* P  = Mm + 16L * 65536;
        float* W2 = P  + 16L * 65536;
        float* WP = W2 + 16L * 4096;

        gemm64<true, false><<<dim3(4, 4, 16), 256, 0, stream>>>(
            x, x, G, 256, 256, 4096, 1048576L, 1048576L, 65536L, nullptr, nullptr);
        gemm64<false, false><<<dim3(4, 12, 16), 256, 0, stream>>>(
            wqkv, G, T, 768, 256, 256, 0L, 65536L, 196608L, nullptr, nullptr);
        attn_kernel<<<128, 256, 0, stream>>>(T, wqkv, temp, Mm, 196608L);
        gemm64<false, false><<<dim3(4, 4, 16), 256, 0, stream>>>(
            wproj, Mm, P, 256, 256, 256, 0L, 65536L, 65536L, nullptr, nullptr);
        w2_kernel<<<16, 256, 0, stream>>>(P, gnb, W2);
        wpre_kernel<<<dim3(16, 16), 256, 0, stream>>>(W2, x, WP);
        gemm64<false, true><<<dim3(64, 4, 16), 256, 0, stream>>>(
            P, x, out, 256, 4096, 256, 65536L, 1048576L, 1048576L, x, WP);
    }
}